// Round 1
// baseline (965.796 us; speedup 1.0000x reference)
//
#include <hip/hip_runtime.h>
#include <hip/hip_fp16.h>
#include <stdint.h>

// sLSTM cell, T=512, B=16, H=4 heads, D=256, G=4 gates. fp32 in/out.
//
// Design:
//  - Recurrence is block-diagonal per head => 64 independent chains (b,head).
//  - 256 persistent blocks = 64 chains x 4 output-dim quarters; each block owns
//    64 dims x 4 gates, with its 256x256 f16 weight slice REGISTER-RESIDENT
//    (128 VGPRs/thread; thread = (dim j_local, k-quarter), k-split reduced by
//    shfl_xor butterfly).
//  - Per-step cross-block h exchange: agent-scope relaxed atomic u32 words,
//    self-validating: hi16 = f16(h), lo16 = step tag. 2-slot ping-pong.
//    No fences needed (payload is inside the atomic word).
//  - Weights pre-scrambled to f16 by a repack kernel into d_ws
//    (needs ws >= 2 MB + 128 KB).
//    Scramble derived from the reference reshape chain:
//    Weff[h,g,dout,din] = rk[h, (din%64)*4+g, dout/64, (dout%64)*4+din/64].

#define NTS 512
#define OUTS_ELEMS (NTS * 16 * 1024)   // 8388608 floats of `outs`

typedef _Float16 half2v __attribute__((ext_vector_type(2)));

__device__ __forceinline__ float fdot2f(uint32_t a, uint32_t b, float c) {
#if __has_builtin(__builtin_amdgcn_fdot2)
  union U { uint32_t u; half2v h; };
  U ua, ub; ua.u = a; ub.u = b;
  return __builtin_amdgcn_fdot2(ua.h, ub.h, c, false);
#else
  __half2 ha, hb;
  *(uint32_t*)&ha = a; *(uint32_t*)&hb = b;
  float2 fa = __half22float2(ha), fb = __half22float2(hb);
  return fmaf(fa.y, fb.y, fmaf(fa.x, fb.x, c));
#endif
}

// One thread per u32 (f16 pair) of the packed weight blob.
// Blob layout (u32 index): (((hq*4 + w)*32 + m)*64 + lane)*4 + dd
//   hq = head*4+q4, w = wave, lane = kq*16 + j_local, n = m*4+dd in [0,128):
//   gate g = n>>5, pair p = n&31; element e in {0,1}: k = kq*64 + 2p + e,
//   dout = q4*64 + w*16 + j_local.
__global__ void repack_weights(const float* __restrict__ rk,
                               uint32_t* __restrict__ wp) {
  int tid = blockIdx.x * 256 + threadIdx.x;   // [0, 524288)
  int dd   = tid & 3;
  int lane = (tid >> 2) & 63;
  int m    = (tid >> 8) & 31;
  int w    = (tid >> 13) & 3;
  int hq   = tid >> 15;                        // head*4 + q4
  int head = hq >> 2, q4 = hq & 3;
  int j_local = lane & 15, kq = lane >> 4;
  int n = m * 4 + dd;
  int g = n >> 5, p = n & 31;
  int dlo = w * 16 + j_local;                  // dout % 64 (gsel = q4)
  uint32_t word = 0;
  #pragma unroll
  for (int e = 0; e < 2; ++e) {
    int klo = 2 * p + e;                       // k % 64
    int d1 = klo * 4 + g;
    int d2 = dlo * 4 + kq;
    float v = rk[head * 262144 + d1 * 1024 + q4 * 256 + d2];
    word |= (uint32_t)__half_as_ushort(__float2half(v)) << (16 * e);
  }
  wp[tid] = word;
}

__global__ __launch_bounds__(256) void slstm_main(
    const float* __restrict__ x, const float* __restrict__ bias,
    const uint32_t* __restrict__ wp, uint32_t* hex,
    float* __restrict__ out) {
  __shared__ __align__(16) unsigned short lh[2][256];

  // XCD-swizzled decode: 4 quarters of a chain share blockIdx%8 (same XCD
  // under round-robin placement — perf heuristic only, correctness is
  // agent-scope either way).
  const int bid = blockIdx.x;
  const int xcd = bid & 7, yy = bid >> 3;
  const int q4 = yy & 3, ii = yy >> 2;
  const int cc = xcd * 8 + ii;                 // chain [0,64)
  const int b = cc >> 2, head = cc & 3;
  const int lane = threadIdx.x & 63, w = threadIdx.x >> 6;
  const int j_local = lane & 15, kq = lane >> 4;
  const int j_abs = q4 * 64 + w * 16 + j_local;
  const int hq = head * 4 + q4;

  // ---- register-resident weights: 128 u32 = 256 f16 ----
  uint32_t wr_[128];
  {
    const uint4* wp4 = (const uint4*)wp;
    int base = ((hq * 4 + w) * 32) * 64 + lane;
    #pragma unroll
    for (int mm = 0; mm < 32; ++mm) {
      uint4 v = wp4[base + mm * 64];
      wr_[mm * 4 + 0] = v.x; wr_[mm * 4 + 1] = v.y;
      wr_[mm * 4 + 2] = v.z; wr_[mm * 4 + 3] = v.w;
    }
  }

  float bg[4];
  #pragma unroll
  for (int g = 0; g < 4; ++g) bg[g] = bias[g * 1024 + head * 256 + j_abs];

  const int xoff0 = b * 4096 + head * 256 + j_abs;
  float xv[4];
  #pragma unroll
  for (int g = 0; g < 4; ++g) xv[g] = x[xoff0 + g * 1024];

  const int rd_idx = cc * 256 + w * 64 + lane;  // word this thread fetches
  const int wr_idx = cc * 256 + j_abs;          // word this thread publishes
  const int out_off = b * 1024 + head * 256 + j_abs;

  float hs = 0.f, cs = 0.f, nns = 0.f, ms = 0.f;

  #pragma unroll 1
  for (int t = 0; t < NTS; ++t) {
    float a0 = 0.f, a1 = 0.f, a2 = 0.f, a3 = 0.f;
    if (t > 0) {
      // --- acquire h_{t-1}: spin on self-validating words ---
      const uint32_t tg = (uint32_t)(t - 1);
      uint32_t* sp = hex + ((t - 1) & 1) * 16384 + rd_idx;
      uint32_t v; int spins = 0;
      for (;;) {
        v = __hip_atomic_load(sp, __ATOMIC_RELAXED, __HIP_MEMORY_SCOPE_AGENT);
        if (__all((v & 0xffffu) == tg) || ++spins > (1 << 14)) break;
      }
      lh[t & 1][w * 64 + lane] = (unsigned short)(v >> 16);
      __syncthreads();
      // --- my k-slice (64 f16 = 32 pairs) via 8x ds_read_b128 ---
      uint32_t hr[32];
      {
        const float4* hp = (const float4*)&lh[t & 1][kq * 64];
        #pragma unroll
        for (int f = 0; f < 8; ++f) {
          float4 fv = hp[f];
          hr[f * 4 + 0] = __float_as_uint(fv.x);
          hr[f * 4 + 1] = __float_as_uint(fv.y);
          hr[f * 4 + 2] = __float_as_uint(fv.z);
          hr[f * 4 + 3] = __float_as_uint(fv.w);
        }
      }
      // --- 4 gate partial dots over 64 k-values ---
      #pragma unroll
      for (int p = 0; p < 32; ++p) {
        uint32_t hh = hr[p];
        a0 = fdot2f(wr_[p],      hh, a0);
        a1 = fdot2f(wr_[32 + p], hh, a1);
        a2 = fdot2f(wr_[64 + p], hh, a2);
        a3 = fdot2f(wr_[96 + p], hh, a3);
      }
      // --- butterfly over the 4 k-quarters (lanes xor 16, 32) ---
      a0 += __shfl_xor(a0, 16, 64); a0 += __shfl_xor(a0, 32, 64);
      a1 += __shfl_xor(a1, 16, 64); a1 += __shfl_xor(a1, 32, 64);
      a2 += __shfl_xor(a2, 16, 64); a2 += __shfl_xor(a2, 32, 64);
      a3 += __shfl_xor(a3, 16, 64); a3 += __shfl_xor(a3, 32, 64);
    }

    float ri = a0 + xv[0] + bg[0];
    float rf = a1 + xv[1] + bg[1];
    float rz = a2 + xv[2] + bg[2];
    float ro = a3 + xv[3] + bg[3];

    // prefetch next step's Wx while gates compute
    float xn0 = 0.f, xn1 = 0.f, xn2 = 0.f, xn3 = 0.f;
    if (t < NTS - 1) {
      int xo = xoff0 + (t + 1) * 65536;
      xn0 = x[xo]; xn1 = x[xo + 1024]; xn2 = x[xo + 2048]; xn3 = x[xo + 3072];
    }

    // state update (matches reference; all(n==0) <=> t==0)
    float lsf = fminf(rf, 0.f) - log1pf(__expf(-fabsf(rf)));
    float lf = ms + lsf;
    float mnew = (t == 0) ? ri : fmaxf(ri, lf);
    float og = 1.f / (1.f + __expf(-ro));
    float ig = __expf(ri - mnew);
    float fg = __expf(lf - mnew);
    float cnew = fg * cs + ig * tanhf(rz);
    float nnew = fg * hs + ig;                  // NB: reference uses h, not n
    float hnew = og * cnew / nnew;
    hs = hnew; cs = cnew; nns = nnew; ms = mnew;

    // publish: outs + exchange word (one lane per dim: kq==0)
    if (kq == 0) {
      out[t * 16384 + out_off] = hnew;
      uint32_t wword =
          ((uint32_t)__half_as_ushort(__float2half(hnew)) << 16) | (uint32_t)t;
      __hip_atomic_store(hex + (t & 1) * 16384 + wr_idx, wword,
                         __ATOMIC_RELAXED, __HIP_MEMORY_SCOPE_AGENT);
    }
    if (t < NTS - 1) { xv[0] = xn0; xv[1] = xn1; xv[2] = xn2; xv[3] = xn3; }
  }

  // final_state: stack (h, c, n, m)
  if (kq == 0) {
    float* fs = out + OUTS_ELEMS;
    int o = b * 1024 + head * 256 + j_abs;
    fs[o] = hs;
    fs[16384 + o] = cs;
    fs[32768 + o] = nns;
    fs[49152 + o] = ms;
  }
}

extern "C" void kernel_launch(void* const* d_in, const int* in_sizes, int n_in,
                              void* d_out, int out_size, void* d_ws,
                              size_t ws_size, hipStream_t stream) {
  const float* x    = (const float*)d_in[0];  // (512,16,4096)
  const float* rk   = (const float*)d_in[1];  // (4,256,4,256)
  const float* bias = (const float*)d_in[2];  // (4,4,256)
  uint32_t* wp  = (uint32_t*)d_ws;                         // 2 MB packed f16
  uint32_t* hex = (uint32_t*)((char*)d_ws + (1u << 21));   // 128 KB exchange
  float* out = (float*)d_out;

  repack_weights<<<2048, 256, 0, stream>>>(rk, wp);
  slstm_main<<<256, 256, 0, stream>>>(x, bias, wp, hex, out);
}

// Round 2
// 933.183 us; speedup vs baseline: 1.0349x; 1.0349x over previous
//
#include <hip/hip_runtime.h>
#include <hip/hip_fp16.h>
#include <stdint.h>

// sLSTM cell, T=512, B=16, H=4 heads, D=256, G=4 gates. fp32 in/out.
//
// R2 design:
//  - 64 chains (b,head) x 4 j-quarter blocks = 256 blocks, 1 block/CU.
//  - NEW mapping: wave w of a block owns k-quarter w for ALL 64 j's the
//    block owns. Each wave spins only on its own quarter's exchange words,
//    packs them through wave-synchronous LDS (no barrier), runs its dots,
//    then ONE __syncthreads before a cross-wave partial reduction.
//  - Wave w==q4 consumes the quarter this block itself publishes -> no
//    global spin for it at all (h_new written to its own LDS pack row at
//    the end of the previous step).
//  - __launch_bounds__(256,1): 1 wave/SIMD -> up to 512 VGPRs, forcing the
//    128-u32 weight slice to be truly register-resident (R1 got 92 VGPRs
//    and re-streamed weights from cache every step).
//  - x prefetch for t+1 issued right after spin success so the next spin's
//    vmcnt(0) polls don't serialize on outstanding HBM loads.
//  - Exchange protocol unchanged (proven): agent-scope relaxed u32,
//    hi16 = f16(h), lo16 = step tag, 2-slot ping-pong.
//  - ws: 2 MB packed f16 weights + 128 KB exchange.

#define NTS 512
#define OUTS_ELEMS (NTS * 16 * 1024)   // 8388608 floats of `outs`

typedef _Float16 half2v __attribute__((ext_vector_type(2)));

__device__ __forceinline__ float fdot2f(uint32_t a, uint32_t b, float c) {
#if __has_builtin(__builtin_amdgcn_fdot2)
  union U { uint32_t u; half2v h; };
  U ua, ub; ua.u = a; ub.u = b;
  return __builtin_amdgcn_fdot2(ua.h, ub.h, c, false);
#else
  __half2 ha, hb;
  *(uint32_t*)&ha = a; *(uint32_t*)&hb = b;
  float2 fa = __half22float2(ha), fb = __half22float2(hb);
  return fmaf(fa.y, fb.y, fmaf(fa.x, fb.x, c));
#endif
}

// Packed blob (u32 index): (((hq*4 + w)*32 + m)*64 + lane)*4 + dd
//   hq = head*4+q4 in [0,16), w = k-quarter wave, lane = j_local in [0,64),
//   n = m*4+dd in [0,128): gate g = n>>5, pair p = n&31.
//   Element e in {0,1}: din = w*64 + 2p+e, dout = q4*64 + lane.
//   Weff[h,g,dout,din] = rk[h, (din%64)*4+g, dout/64, (dout%64)*4+din/64]
//     -> rk[head*262144 + ((2p+e)*4+g)*1024 + q4*256 + lane*4 + w]
__global__ void repack_weights(const float* __restrict__ rk,
                               uint32_t* __restrict__ wp) {
  int tid = blockIdx.x * 256 + threadIdx.x;   // [0, 524288)
  int dd   = tid & 3;
  int lane = (tid >> 2) & 63;
  int m    = (tid >> 8) & 31;
  int w    = (tid >> 13) & 3;
  int hq   = tid >> 15;                        // head*4 + q4
  int head = hq >> 2, q4 = hq & 3;
  int n = m * 4 + dd;
  int g = n >> 5, p = n & 31;
  uint32_t word = 0;
  #pragma unroll
  for (int e = 0; e < 2; ++e) {
    int klo = 2 * p + e;                       // din % 64
    float v = rk[head * 262144 + (klo * 4 + g) * 1024 + q4 * 256 + lane * 4 + w];
    word |= (uint32_t)__half_as_ushort(__float2half(v)) << (16 * e);
  }
  wp[tid] = word;
}

__global__ __launch_bounds__(256, 1) void slstm_main(
    const float* __restrict__ x, const float* __restrict__ bias,
    const uint32_t* __restrict__ wp, uint32_t* hex,
    float* __restrict__ out) {
  // lh[w][*]: wave-private h-f16 pack rows (wave-synchronous, no barrier).
  // pa[slot][w][lane]: cross-wave partial sums, ping-pong on t&1.
  __shared__ __align__(16) unsigned short lh[4][64];
  __shared__ __align__(16) float4 pa[2][4][64];

  // XCD swizzle: 4 quarters of a chain share blockIdx%8 (round-robin XCD).
  const int bid = blockIdx.x;
  const int xcd = bid & 7, yy = bid >> 3;
  const int q4 = yy & 3, ii = yy >> 2;
  const int cc = xcd * 8 + ii;                 // chain [0,64)
  const int b = cc >> 2, head = cc & 3;
  const int lane = threadIdx.x & 63, w = threadIdx.x >> 6;
  const int hq = head * 4 + q4;
  const int j_abs = q4 * 64 + lane;            // this lane's output dim
  const bool is_pub = (w == 0);                // publishes out + exchange
  const bool is_own = (w == q4);               // k-quarter == own j-quarter
  const bool needs_gates = is_pub || is_own;

  // ---- register-resident weights: 128 u32 = 256 f16 ----
  uint32_t wr_[128];
  {
    const uint4* wp4 = (const uint4*)wp;
    int base = ((hq * 4 + w) * 32) * 64 + lane;
    #pragma unroll
    for (int mm = 0; mm < 32; ++mm) {
      uint4 v = wp4[base + mm * 64];
      wr_[mm * 4 + 0] = v.x; wr_[mm * 4 + 1] = v.y;
      wr_[mm * 4 + 2] = v.z; wr_[mm * 4 + 3] = v.w;
    }
  }

  float bg[4];
  #pragma unroll
  for (int g = 0; g < 4; ++g) bg[g] = bias[g * 1024 + head * 256 + j_abs];

  const int xoff0 = b * 4096 + head * 256 + j_abs;
  float xv[4] = {0.f, 0.f, 0.f, 0.f};
  if (needs_gates) {
    #pragma unroll
    for (int g = 0; g < 4; ++g) xv[g] = x[xoff0 + g * 1024];
  }

  const int rd_idx = cc * 256 + w * 64 + lane;   // word this wave spins on
  const int wr_idx = cc * 256 + j_abs;           // word wave 0 publishes
  const int out_off = b * 1024 + head * 256 + j_abs;

  float hs = 0.f, cs = 0.f, nns = 0.f, ms = 0.f;

  #pragma unroll 1
  for (int t = 0; t < NTS; ++t) {
    float A0 = 0.f, A1 = 0.f, A2 = 0.f, A3 = 0.f;
    float xn0 = 0.f, xn1 = 0.f, xn2 = 0.f, xn3 = 0.f;
    if (t > 0) {
      if (!is_own) {
        // --- acquire h_{t-1} quarter w: spin on self-validating words ---
        const uint32_t tg = (uint32_t)(t - 1);
        uint32_t* sp = hex + ((t - 1) & 1) * 16384 + rd_idx;
        uint32_t v; int spins = 0;
        for (;;) {
          v = __hip_atomic_load(sp, __ATOMIC_RELAXED, __HIP_MEMORY_SCOPE_AGENT);
          if (__all((v & 0xffffu) == tg) || ++spins > (1 << 15)) break;
        }
        lh[w][lane] = (unsigned short)(v >> 16);
      }
      // prefetch next step's Wx now: drains during dots so the next spin's
      // vmcnt(0) polls don't wait on it
      if (needs_gates && t < NTS - 1) {
        int xo = xoff0 + (t + 1) * 65536;
        xn0 = x[xo]; xn1 = x[xo + 1024]; xn2 = x[xo + 2048]; xn3 = x[xo + 3072];
      }
      // --- wave-synchronous pack read: 8x ds_read_b128, broadcast addr ---
      float a0 = 0.f, a1 = 0.f, a2 = 0.f, a3 = 0.f;
      {
        uint32_t hr[32];
        const float4* hp = (const float4*)&lh[w][0];
        #pragma unroll
        for (int f = 0; f < 8; ++f) {
          float4 fv = hp[f];
          hr[f * 4 + 0] = __float_as_uint(fv.x);
          hr[f * 4 + 1] = __float_as_uint(fv.y);
          hr[f * 4 + 2] = __float_as_uint(fv.z);
          hr[f * 4 + 3] = __float_as_uint(fv.w);
        }
        #pragma unroll
        for (int p = 0; p < 32; ++p) {
          uint32_t hh = hr[p];
          a0 = fdot2f(wr_[p],      hh, a0);
          a1 = fdot2f(wr_[32 + p], hh, a1);
          a2 = fdot2f(wr_[64 + p], hh, a2);
          a3 = fdot2f(wr_[96 + p], hh, a3);
        }
      }
      pa[t & 1][w][lane] = make_float4(a0, a1, a2, a3);
      __syncthreads();
      if (needs_gates) {
        #pragma unroll
        for (int ww = 0; ww < 4; ++ww) {
          float4 pv = pa[t & 1][ww][lane];
          A0 += pv.x; A1 += pv.y; A2 += pv.z; A3 += pv.w;
        }
      }
    } else {
      if (needs_gates) {
        int xo = xoff0 + 65536;
        xn0 = x[xo]; xn1 = x[xo + 1024]; xn2 = x[xo + 2048]; xn3 = x[xo + 3072];
      }
    }

    if (needs_gates) {
      float ri = A0 + xv[0] + bg[0];
      float rf = A1 + xv[1] + bg[1];
      float rz = A2 + xv[2] + bg[2];
      float ro = A3 + xv[3] + bg[3];

      // state update (matches reference; all(n==0) <=> t==0)
      float lsf = fminf(rf, 0.f) - log1pf(__expf(-fabsf(rf)));
      float lf = ms + lsf;
      float mnew = (t == 0) ? ri : fmaxf(ri, lf);
      float og = 1.f / (1.f + __expf(-ro));
      float ig = __expf(ri - mnew);
      float fg = __expf(lf - mnew);
      float cnew = fg * cs + ig * tanhf(rz);
      float nnew = fg * hs + ig;                // reference uses h here
      float hnew = og * cnew / nnew;
      hs = hnew; cs = cnew; nns = nnew; ms = mnew;

      unsigned short hf = __half_as_ushort(__float2half(hnew));
      if (is_pub) {
        out[t * 16384 + out_off] = hnew;
        uint32_t wword = ((uint32_t)hf << 16) | (uint32_t)t;
        __hip_atomic_store(hex + (t & 1) * 16384 + wr_idx, wword,
                           __ATOMIC_RELAXED, __HIP_MEMORY_SCOPE_AGENT);
      }
      if (is_own) {
        lh[w][lane] = hf;   // own-quarter short-circuit for step t+1
      }
      xv[0] = xn0; xv[1] = xn1; xv[2] = xn2; xv[3] = xn3;
    }
  }

  // final_state: stack (h, c, n, m)
  if (is_pub) {
    float* fs = out + OUTS_ELEMS;
    fs[out_off] = hs;
    fs[16384 + out_off] = cs;
    fs[32768 + out_off] = nns;
    fs[49152 + out_off] = ms;
  }
}

extern "C" void kernel_launch(void* const* d_in, const int* in_sizes, int n_in,
                              void* d_out, int out_size, void* d_ws,
                              size_t ws_size, hipStream_t stream) {
  const float* x    = (const float*)d_in[0];  // (512,16,4096)
  const float* rk   = (const float*)d_in[1];  // (4,256,4,256)
  const float* bias = (const float*)d_in[2];  // (4,4,256)
  uint32_t* wp  = (uint32_t*)d_ws;                         // 2 MB packed f16
  uint32_t* hex = (uint32_t*)((char*)d_ws + (1u << 21));   // 128 KB exchange
  float* out = (float*)d_out;

  repack_weights<<<2048, 256, 0, stream>>>(rk, wp);
  slstm_main<<<256, 256, 0, stream>>>(x, bias, wp, hex, out);
}